// Round 9
// baseline (190.727 us; speedup 1.0000x reference)
//
#include <hip/hip_runtime.h>
#include <math.h>

// Problem constants (B=16, C=3, H=W=512) -> 48 "rows" (images) of L = 262144 elements.
constexpr int W = 512;
constexpr int HIMG = 512;
constexpr int L = 1 << 18;                // elements per row
constexpr int LOG2L = 18;
constexpr int TPB = 256;
constexpr int TILE = 2048;                // elements per scatter tile (= 4 scanlines)
constexpr int TILES_PER_ROW = L / TILE;   // 128
constexpr int WORDS_PER_TILE = TILE / 64; // 32
constexpr int SPB = 32;                   // scanlines per fused-mask block
constexpr int HALO = 3;
constexpr int HBUF = SPB + 2 * HALO;      // 38
constexpr int LBLK = 64;                  // loss blocks per row
constexpr int CHUNK = L / LBLK;           // 4096 elements per loss block (generic path)
constexpr int G = CHUNK / (TPB * 4);      // 4 float4 groups per thread (generic path)
constexpr int JPB = 8 * TPB;              // 2048 j's per loss block per sweep (fast path)

typedef unsigned long long ull;

// softplus via native v_exp_f32 / v_log_f32 (abs err ~1e-6; threshold 3.6e-2)
__device__ __forceinline__ float softplus_f(float v) {
    return fmaxf(v, 0.0f) +
           0.6931471805599453f *
               __builtin_amdgcn_logf(1.0f + __builtin_amdgcn_exp2f(-fabsf(v) * 1.4426950408889634f));
}

__device__ __forceinline__ ull hdil7(ull prev, ull cur, ull next) {
    ull r = cur;
    r |= (cur >> 1) | (next << 63);
    r |= (cur >> 2) | (next << 62);
    r |= (cur >> 3) | (next << 61);
    r |= (cur << 1) | (prev >> 63);
    r |= (cur << 2) | (prev >> 62);
    r |= (cur << 3) | (prev >> 61);
    return r;
}

template <typename T>
__device__ __forceinline__ T sel8(const T* a, int k) {
    return k == 0 ? a[0] : k == 1 ? a[1] : k == 2 ? a[2] : k == 3 ? a[3]
         : k == 4 ? a[4] : k == 5 ? a[5] : k == 6 ? a[6] : a[7];
}

// ------ K1: fused masks + 7x7 dilation + per-tile counts. One block = 32 scanlines. ------
__global__ __launch_bounds__(TPB)
void fused_mask_kernel(const float* __restrict__ x, const float* __restrict__ t,
                       ull* __restrict__ mT, ull* __restrict__ mFp, ull* __restrict__ mNeg,
                       int* __restrict__ cPos, int* __restrict__ cFp, int* __restrict__ cNeg,
                       float* __restrict__ out) {
    if (blockIdx.x == 0 && threadIdx.x == 0) out[0] = 0.0f;  // d_out is poisoned; zero it
    int b = blockIdx.x;
    int img = b >> 4;              // 16 blocks per image
    int y0 = (b & 15) * SPB;       // image-local scanline base
    int gs0 = img * HIMG + y0;     // global scanline index of own base

    __shared__ ull hbuf[HBUF][8];  // h-dilated words incl. halo
    __shared__ ull tbuf[SPB][8];
    __shared__ ull xbuf[SPB][8];

    int lane = threadIdx.x & 63;
    int wv = threadIdx.x >> 6;     // wave 0..3
    int ylo = (y0 - HALO < 0) ? 0 : y0 - HALO;
    int yhi = (y0 + SPB - 1 + HALO > HIMG - 1) ? HIMG - 1 : y0 + SPB - 1 + HALO;

    for (int yl = ylo + wv; yl <= yhi; yl += 4) {
        int gbase = (img * HIMG + yl) * W;
        bool own = (yl >= y0) && (yl < y0 + SPB);
        ull wt[8], wx[8], h[8];
#pragma unroll
        for (int k = 0; k < 8; ++k) wt[k] = __ballot(t[gbase + k * 64 + lane] > 0.0f);
        if (own) {
#pragma unroll
            for (int k = 0; k < 8; ++k) wx[k] = __ballot(x[gbase + k * 64 + lane] > 0.0f);
        }
#pragma unroll
        for (int k = 0; k < 8; ++k) {
            ull cur = wt[k];
            ull prev = k ? wt[k - 1]
                         : ((((cur >> 1) & 1ull) << 63) | (((cur >> 2) & 1ull) << 62) |
                            (((cur >> 3) & 1ull) << 61));
            ull next = (k < 7) ? wt[k + 1]
                               : (((cur >> 62) & 1ull) | (((cur >> 61) & 1ull) << 1) |
                                  (((cur >> 60) & 1ull) << 2));
            h[k] = hdil7(prev, cur, next);
        }
        int hy = yl - (y0 - HALO);
        int k = lane & 7;
        if (lane < 8) {
            hbuf[hy][k] = sel8(h, k);
        } else if (own && lane < 16) {
            tbuf[yl - y0][k] = sel8(wt, k);
            mT[(img * HIMG + yl) * 8 + k] = sel8(wt, k);
        } else if (own && lane < 24) {
            xbuf[yl - y0][k] = sel8(wx, k);
        }
    }
    __syncthreads();

    // phase 2: vertical dilation + per-word popcounts; thread = one own word
    int tid = threadIdx.x;
    int ys = tid >> 3;   // own scanline offset 0..31
    int c = tid & 7;
    int y = y0 + ys;
    ull wa = 0;
#pragma unroll
    for (int d = -3; d <= 3; ++d) {
        int yy = y + d;
        yy = yy < 0 ? -yy : (yy > HIMG - 1 ? 2 * (HIMG - 1) - yy : yy);
        wa |= hbuf[yy - (y0 - HALO)][c];
    }
    ull tw = tbuf[ys][c];
    ull fp = xbuf[ys][c] & ~wa;
    ull ng = ~wa;
    int gw = gs0 * 8 + tid;
    mFp[gw] = fp;
    mNeg[gw] = ng;
    int pT = __popcll(tw), pF = __popcll(fp), pN = __popcll(ng);
#pragma unroll
    for (int m = 1; m < 32; m <<= 1) {
        pT += __shfl_xor(pT, m, 64);
        pF += __shfl_xor(pF, m, 64);
        pN += __shfl_xor(pN, m, 64);
    }
    if ((lane & 31) == 0) {
        int tile = img * TILES_PER_ROW + (y0 >> 2) + (tid >> 5);
        cPos[tile] = pT; cFp[tile] = pF; cNeg[tile] = pN;
    }
}

// ------ K2: per-row scan of tile counts + magic divisors (tiny) ------
__global__ void scan_kernel(const int* __restrict__ cPos, const int* __restrict__ cFp,
                            const int* __restrict__ cNeg,
                            int* __restrict__ oPos, int* __restrict__ oCh,
                            int* __restrict__ rCp, int* __restrict__ rCc,
                            ull* __restrict__ rMp, ull* __restrict__ rMc,
                            int* __restrict__ rUseFp) {
    int r = blockIdx.x;
    int tid = threadIdx.x;  // blockDim == TILES_PER_ROW
    __shared__ int ssp[TILES_PER_ROW], ssf[TILES_PER_ROW], ssn[TILES_PER_ROW];
    int myp = cPos[r * TILES_PER_ROW + tid];
    int myf = cFp[r * TILES_PER_ROW + tid];
    int myn = cNeg[r * TILES_PER_ROW + tid];
    ssp[tid] = myp; ssf[tid] = myf; ssn[tid] = myn;
    __syncthreads();
    for (int off = 1; off < TILES_PER_ROW; off <<= 1) {
        int ap = 0, af = 0, an = 0;
        if (tid >= off) { ap = ssp[tid - off]; af = ssf[tid - off]; an = ssn[tid - off]; }
        __syncthreads();
        if (tid >= off) { ssp[tid] += ap; ssf[tid] += af; ssn[tid] += an; }
        __syncthreads();
    }
    int cp = ssp[TILES_PER_ROW - 1], cf = ssf[TILES_PER_ROW - 1], cn = ssn[TILES_PER_ROW - 1];
    bool useFp = cf > 0;
    int tile = r * TILES_PER_ROW + tid;
    oPos[tile] = ssp[tid] - myp;
    oCh[tile] = useFp ? (ssf[tid] - myf) : (ssn[tid] - myn);
    if (tid == 0) {
        int cc = useFp ? cf : cn;
        rCp[r] = cp; rCc[r] = cc; rUseFp[r] = useFp ? 1 : 0;
        ull dp_ = (ull)(cp > 0 ? cp : 1);
        ull dc_ = (ull)(cc > 0 ? cc : 1);
        rMp[r] = ((1ull << 40) + dp_ - 1) / dp_;  // exact floor(a/d) for a < 2^22
        rMc[r] = ((1ull << 40) + dc_ - 1) / dc_;
    }
}

// ------ K3: stable scatter-compaction with LDS-staged coalesced stores ------
__global__ __launch_bounds__(TPB)
void scatter_kernel(const float* __restrict__ x, const ull* __restrict__ mT,
                    const ull* __restrict__ mFp, const ull* __restrict__ mNeg,
                    const int* __restrict__ oPos, const int* __restrict__ oCh,
                    const int* __restrict__ rUseFp,
                    float* __restrict__ xp, float* __restrict__ xf) {
    int tile = blockIdx.x;
    int tid = threadIdx.x;
    int r = tile >> 7;
    bool useFp = rUseFp[r] != 0;
    int widx = tile * WORDS_PER_TILE + (tid >> 3);
    int shift = (tid & 7) * 8;
    unsigned bT = (unsigned)(mT[widx] >> shift) & 0xFF;
    ull chw = useFp ? mFp[widx] : mNeg[widx];
    unsigned bCh = (unsigned)(chw >> shift) & 0xFF;
    const float4* x4 = (const float4*)x;
    int b4 = tile * (TILE / 4) + tid * 2;
    float4 a = x4[b4], b = x4[b4 + 1];
    float xv[8] = {a.x, a.y, a.z, a.w, b.x, b.y, b.z, b.w};
    int p = __popc(bT), c = __popc(bCh);
    __shared__ int s[TPB];
    __shared__ float bufP[TILE], bufC[TILE];
    int v = p | (c << 16);
    s[tid] = v;
    __syncthreads();
    for (int off = 1; off < TPB; off <<= 1) {
        int add = tid >= off ? s[tid - off] : 0;
        __syncthreads();
        s[tid] += add;
        __syncthreads();
    }
    int excl = s[tid] - v;
    int ep = excl & 0xFFFF;
    int ec = excl >> 16;
#pragma unroll
    for (int e = 0; e < 8; ++e) {
        if ((bT >> e) & 1) bufP[ep++] = xv[e];
        if ((bCh >> e) & 1) bufC[ec++] = xv[e];
    }
    __syncthreads();
    int tot = s[TPB - 1];
    int P = tot & 0xFFFF, C = tot >> 16;
    int rL = r << LOG2L;
    int pbase = rL + oPos[tile];
    for (int i = tid; i < P; i += TPB) xp[pbase + i] = bufP[i];
    int cbase = rL + oCh[tile];
    for (int i = tid; i < C; i += TPB) xf[cbase + i] = bufC[i];
}

// ------ K4: loss. Fast path: dup-centric pure streaming (cc==0, 3*cp>=L). ------
__global__ __launch_bounds__(TPB)
void loss_kernel(const float* __restrict__ x, const ull* __restrict__ mT,
                 const float* __restrict__ xp, const float* __restrict__ xf,
                 const int* __restrict__ rCp, const int* __restrict__ rCc,
                 const ull* __restrict__ rMp, const ull* __restrict__ rMc,
                 float* __restrict__ out, double inv_ntot) {
    int b = blockIdx.x;
    int r = b >> 6;                 // LBLK=64 blocks per row
    int blk = b & 63;
    int rL = r << LOG2L;
    int cp = rCp[r], cc = rCc[r];   // wave-uniform scalars
    const float* xr = x + rL;
    const float* xpr = xp + rL;
    const ull* mtr = mT + (rL >> 6);
    int tid = threadIdx.x;
    float local = 0.0f;

    if (cc == 0 && cp * 3 >= L) {
        // dup_fp == -5 everywhere; each xp[j] serves l = j, j+cp, (j+2cp if < L).
        // All loads are coalesced streams; dp-only terms factored (x n_j).
        for (int base = blk * JPB; base < cp; base += 64 * JPB) {
#pragma unroll
            for (int it = 0; it < 8; ++it) {
                int j = base + it * TPB + tid;
                if (j < cp) {
                    float dp = xpr[j];
                    int l2 = j + cp, l3 = l2 + cp;
                    bool b2 = l2 < L, b3 = l3 < L;
                    float x1 = xr[j];
                    float x2 = b2 ? xr[l2] : 0.0f;
                    float x3 = b3 ? xr[l3] : 0.0f;
                    unsigned t1 = (unsigned)(mtr[j >> 6] >> (j & 63)) & 1u;
                    unsigned t2 = b2 ? ((unsigned)(mtr[l2 >> 6] >> (l2 & 63)) & 1u) : 0u;
                    unsigned t3 = b3 ? ((unsigned)(mtr[l3 >> 6] >> (l3 & 63)) & 1u) : 0u;
                    float n = 1.0f + (b2 ? 1.0f : 0.0f) + (b3 ? 1.0f : 0.0f);
                    float sim1 = dp * x1, sim2 = dp * x2, sim3 = dp * x3;
                    float e = softplus_f(sim1) - (t1 ? sim1 : 0.0f);
                    e += b2 ? (softplus_f(sim2) - (t2 ? sim2 : 0.0f)) : 0.0f;
                    e += b3 ? (softplus_f(sim3) - (t3 ? sim3 : 0.0f)) : 0.0f;
                    e += n * (softplus_f(-dp) + 0.1f * softplus_f(-5.0f * dp));
                    local += e;
                }
            }
        }
    } else {
        // generic element-centric path (magic-mod gathers); correctness fallback
        int cb = blk * CHUNK;
        ull Mp = rMp[r], Mc = rMc[r];
        const float* xfr = xf + rL;
        const float4* x4 = (const float4*)(xr + cb);
#pragma unroll
        for (int g = 0; g < G; ++g) {
            int o4 = g * TPB + tid;
            unsigned l = (unsigned)(cb + (o4 << 2));
            float4 xv = x4[o4];
            unsigned tb = (unsigned)(mtr[l >> 6] >> (l & 63)) & 0xFu;
            float dps[4], dfs[4];
            if (cp > 0) {
                unsigned d = (unsigned)cp;
                unsigned q = (unsigned)(((ull)l * Mp) >> 40);
                unsigned m0 = l - q * d;
                unsigned m1 = m0 + 1; if (m1 == d) m1 = 0;
                unsigned m2 = m1 + 1; if (m2 == d) m2 = 0;
                unsigned m3 = m2 + 1; if (m3 == d) m3 = 0;
                dps[0] = xpr[m0]; dps[1] = xpr[m1]; dps[2] = xpr[m2]; dps[3] = xpr[m3];
            } else {
                dps[0] = dps[1] = dps[2] = dps[3] = 5.0f;
            }
            if (cc > 0) {
                unsigned d = (unsigned)cc;
                unsigned q = (unsigned)(((ull)l * Mc) >> 40);
                unsigned m0 = l - q * d;
                unsigned m1 = m0 + 1; if (m1 == d) m1 = 0;
                unsigned m2 = m1 + 1; if (m2 == d) m2 = 0;
                unsigned m3 = m2 + 1; if (m3 == d) m3 = 0;
                dfs[0] = xfr[m0]; dfs[1] = xfr[m1]; dfs[2] = xfr[m2]; dfs[3] = xfr[m3];
            } else {
                dfs[0] = dfs[1] = dfs[2] = dfs[3] = -5.0f;
            }
            float xs[4] = {xv.x, xv.y, xv.z, xv.w};
#pragma unroll
            for (int k = 0; k < 4; ++k) {
                float dp = dps[k];
                float sim = dp * xs[k];
                float e = softplus_f(sim) + softplus_f(-dp) + 0.1f * softplus_f(dp * dfs[k]);
                if ((tb >> k) & 1) e -= sim;
                local += e;
            }
        }
    }

    // ---- wave shuffle reduce, then tiny LDS combine ----
#pragma unroll
    for (int m = 1; m < 64; m <<= 1) local += __shfl_xor(local, m, 64);
    __shared__ double sw[4];
    int lane = tid & 63, wv = tid >> 6;
    if (lane == 0) sw[wv] = (double)local;
    __syncthreads();
    if (tid == 0) {
        double s = sw[0] + sw[1] + sw[2] + sw[3];
        atomicAdd(out, (float)(s * inv_ntot));
    }
}

extern "C" void kernel_launch(void* const* d_in, const int* in_sizes, int n_in,
                              void* d_out, int out_size, void* d_ws, size_t ws_size,
                              hipStream_t stream) {
    const float* x = (const float*)d_in[0];
    const float* t = (const float*)d_in[1];
    float* out = (float*)d_out;

    int ntot = in_sizes[0];          // 12,582,912
    int R = ntot >> LOG2L;           // 48
    int numTiles = ntot / TILE;      // 6144
    int nwords = ntot / 64;          // 196,608
    int nMaskBlk = ntot / (SPB * W); // 768

    char* ws = (char*)d_ws;
    size_t off = 0;
    auto alloc = [&](size_t bytes) {
        size_t p = off;
        off = (off + bytes + 255) & ~(size_t)255;
        return (void*)(ws + p);
    };
    ull* mT   = (ull*)alloc((size_t)nwords * 8);
    ull* mFp  = (ull*)alloc((size_t)nwords * 8);
    ull* mNeg = (ull*)alloc((size_t)nwords * 8);
    int* cPos = (int*)alloc(numTiles * sizeof(int));
    int* cFp  = (int*)alloc(numTiles * sizeof(int));
    int* cNeg = (int*)alloc(numTiles * sizeof(int));
    int* oPos = (int*)alloc(numTiles * sizeof(int));
    int* oCh  = (int*)alloc(numTiles * sizeof(int));
    int* rCp = (int*)alloc(R * sizeof(int));
    int* rCc = (int*)alloc(R * sizeof(int));
    int* rUseFp = (int*)alloc(R * sizeof(int));
    ull* rMp = (ull*)alloc(R * sizeof(ull));
    ull* rMc = (ull*)alloc(R * sizeof(ull));
    float* xp = (float*)alloc((size_t)ntot * sizeof(float));
    float* xf = (float*)alloc((size_t)ntot * sizeof(float));

    fused_mask_kernel<<<nMaskBlk, TPB, 0, stream>>>(x, t, mT, mFp, mNeg, cPos, cFp, cNeg, out);
    scan_kernel<<<R, TILES_PER_ROW, 0, stream>>>(cPos, cFp, cNeg, oPos, oCh,
                                                 rCp, rCc, rMp, rMc, rUseFp);
    scatter_kernel<<<numTiles, TPB, 0, stream>>>(x, mT, mFp, mNeg, oPos, oCh, rUseFp, xp, xf);
    loss_kernel<<<R * LBLK, TPB, 0, stream>>>(x, mT, xp, xf, rCp, rCc, rMp, rMc, out,
                                              1.0 / (double)ntot);
}

// Round 10
// 172.476 us; speedup vs baseline: 1.1058x; 1.1058x over previous
//
#include <hip/hip_runtime.h>
#include <math.h>

// Problem constants (B=16, C=3, H=W=512) -> 48 "rows" (images) of L = 262144 elements.
constexpr int W = 512;
constexpr int HIMG = 512;
constexpr int L = 1 << 18;                // elements per row
constexpr int LOG2L = 18;
constexpr int TPB = 256;
constexpr int TILE = 2048;                // elements per scatter tile (= 4 scanlines)
constexpr int TILES_PER_ROW = L / TILE;   // 128
constexpr int WORDS_PER_ROW = L / 64;     // 4096
constexpr int WORDS_PER_TILE = TILE / 64; // 32
constexpr int SPB = 32;                   // scanlines per fused-mask block
constexpr int HALO = 3;
constexpr int HBUF = SPB + 2 * HALO;      // 38
constexpr int LBLK = 64;                  // loss blocks per row
constexpr int CHUNK = L / LBLK;           // 4096 elements per loss block (generic path)
constexpr int G = CHUNK / (TPB * 4);      // 4 float4 groups per thread (generic path)
constexpr int JT = 8;                     // j's per thread (fast path)
constexpr int JBLK = TPB * JT;            // 2048 j's per block per sweep

typedef unsigned long long ull;

// softplus via native v_exp_f32 / v_log_f32 (abs err ~1e-6; threshold 3.6e-2)
__device__ __forceinline__ float softplus_f(float v) {
    return fmaxf(v, 0.0f) +
           0.6931471805599453f *
               __builtin_amdgcn_logf(1.0f + __builtin_amdgcn_exp2f(-fabsf(v) * 1.4426950408889634f));
}

__device__ __forceinline__ ull hdil7(ull prev, ull cur, ull next) {
    ull r = cur;
    r |= (cur >> 1) | (next << 63);
    r |= (cur >> 2) | (next << 62);
    r |= (cur >> 3) | (next << 61);
    r |= (cur << 1) | (prev >> 63);
    r |= (cur << 2) | (prev >> 62);
    r |= (cur << 3) | (prev >> 61);
    return r;
}

template <typename T>
__device__ __forceinline__ T sel8(const T* a, int k) {
    return k == 0 ? a[0] : k == 1 ? a[1] : k == 2 ? a[2] : k == 3 ? a[3]
         : k == 4 ? a[4] : k == 5 ? a[5] : k == 6 ? a[6] : a[7];
}

// ------ K1: fused masks + 7x7 dilation + per-tile counts. One block = 32 scanlines. ------
__global__ __launch_bounds__(TPB)
void fused_mask_kernel(const float* __restrict__ x, const float* __restrict__ t,
                       ull* __restrict__ mT, ull* __restrict__ mFp, ull* __restrict__ mNeg,
                       int* __restrict__ cPos, int* __restrict__ cFp, int* __restrict__ cNeg,
                       double* __restrict__ rowAcc) {
    if (blockIdx.x == 0 && threadIdx.x < 48) rowAcc[threadIdx.x] = 0.0;  // zero loss slots
    int b = blockIdx.x;
    int img = b >> 4;              // 16 blocks per image
    int y0 = (b & 15) * SPB;       // image-local scanline base
    int gs0 = img * HIMG + y0;     // global scanline index of own base

    __shared__ ull hbuf[HBUF][8];  // h-dilated words incl. halo
    __shared__ ull tbuf[SPB][8];
    __shared__ ull xbuf[SPB][8];

    int lane = threadIdx.x & 63;
    int wv = threadIdx.x >> 6;     // wave 0..3
    int ylo = (y0 - HALO < 0) ? 0 : y0 - HALO;
    int yhi = (y0 + SPB - 1 + HALO > HIMG - 1) ? HIMG - 1 : y0 + SPB - 1 + HALO;

    for (int yl = ylo + wv; yl <= yhi; yl += 4) {
        int gbase = (img * HIMG + yl) * W;
        bool own = (yl >= y0) && (yl < y0 + SPB);
        ull wt[8], wx[8], h[8];
#pragma unroll
        for (int k = 0; k < 8; ++k) wt[k] = __ballot(t[gbase + k * 64 + lane] > 0.0f);
        if (own) {
#pragma unroll
            for (int k = 0; k < 8; ++k) wx[k] = __ballot(x[gbase + k * 64 + lane] > 0.0f);
        }
#pragma unroll
        for (int k = 0; k < 8; ++k) {
            ull cur = wt[k];
            ull prev = k ? wt[k - 1]
                         : ((((cur >> 1) & 1ull) << 63) | (((cur >> 2) & 1ull) << 62) |
                            (((cur >> 3) & 1ull) << 61));
            ull next = (k < 7) ? wt[k + 1]
                               : (((cur >> 62) & 1ull) | (((cur >> 61) & 1ull) << 1) |
                                  (((cur >> 60) & 1ull) << 2));
            h[k] = hdil7(prev, cur, next);
        }
        int hy = yl - (y0 - HALO);
        int k = lane & 7;
        if (lane < 8) {
            hbuf[hy][k] = sel8(h, k);
        } else if (own && lane < 16) {
            tbuf[yl - y0][k] = sel8(wt, k);
            mT[(img * HIMG + yl) * 8 + k] = sel8(wt, k);
        } else if (own && lane < 24) {
            xbuf[yl - y0][k] = sel8(wx, k);
        }
    }
    __syncthreads();

    // phase 2: vertical dilation + per-word popcounts; thread = one own word
    int tid = threadIdx.x;
    int ys = tid >> 3;   // own scanline offset 0..31
    int c = tid & 7;
    int y = y0 + ys;
    ull wa = 0;
#pragma unroll
    for (int d = -3; d <= 3; ++d) {
        int yy = y + d;
        yy = yy < 0 ? -yy : (yy > HIMG - 1 ? 2 * (HIMG - 1) - yy : yy);
        wa |= hbuf[yy - (y0 - HALO)][c];
    }
    ull tw = tbuf[ys][c];
    ull fp = xbuf[ys][c] & ~wa;
    ull ng = ~wa;
    int gw = gs0 * 8 + tid;
    mFp[gw] = fp;
    mNeg[gw] = ng;
    int pT = __popcll(tw), pF = __popcll(fp), pN = __popcll(ng);
#pragma unroll
    for (int m = 1; m < 32; m <<= 1) {
        pT += __shfl_xor(pT, m, 64);
        pF += __shfl_xor(pF, m, 64);
        pN += __shfl_xor(pN, m, 64);
    }
    if ((lane & 31) == 0) {
        int tile = img * TILES_PER_ROW + (y0 >> 2) + (tid >> 5);
        cPos[tile] = pT; cFp[tile] = pF; cNeg[tile] = pN;
    }
}

// ------ K2: per-row scan of tile counts + magic divisors (tiny) ------
__global__ void scan_kernel(const int* __restrict__ cPos, const int* __restrict__ cFp,
                            const int* __restrict__ cNeg,
                            int* __restrict__ oPos, int* __restrict__ oCh,
                            int* __restrict__ rCp, int* __restrict__ rCc,
                            ull* __restrict__ rMp, ull* __restrict__ rMc,
                            int* __restrict__ rUseFp) {
    int r = blockIdx.x;
    int tid = threadIdx.x;  // blockDim == TILES_PER_ROW
    __shared__ int ssp[TILES_PER_ROW], ssf[TILES_PER_ROW], ssn[TILES_PER_ROW];
    int myp = cPos[r * TILES_PER_ROW + tid];
    int myf = cFp[r * TILES_PER_ROW + tid];
    int myn = cNeg[r * TILES_PER_ROW + tid];
    ssp[tid] = myp; ssf[tid] = myf; ssn[tid] = myn;
    __syncthreads();
    for (int off = 1; off < TILES_PER_ROW; off <<= 1) {
        int ap = 0, af = 0, an = 0;
        if (tid >= off) { ap = ssp[tid - off]; af = ssf[tid - off]; an = ssn[tid - off]; }
        __syncthreads();
        if (tid >= off) { ssp[tid] += ap; ssf[tid] += af; ssn[tid] += an; }
        __syncthreads();
    }
    int cp = ssp[TILES_PER_ROW - 1], cf = ssf[TILES_PER_ROW - 1], cn = ssn[TILES_PER_ROW - 1];
    bool useFp = cf > 0;
    int tile = r * TILES_PER_ROW + tid;
    oPos[tile] = ssp[tid] - myp;
    oCh[tile] = useFp ? (ssf[tid] - myf) : (ssn[tid] - myn);
    if (tid == 0) {
        int cc = useFp ? cf : cn;
        rCp[r] = cp; rCc[r] = cc; rUseFp[r] = useFp ? 1 : 0;
        ull dp_ = (ull)(cp > 0 ? cp : 1);
        ull dc_ = (ull)(cc > 0 ? cc : 1);
        rMp[r] = ((1ull << 40) + dp_ - 1) / dp_;  // exact floor(a/d) for a < 2^22
        rMc[r] = ((1ull << 40) + dc_ - 1) / dc_;
    }
}

// ------ K3: stable scatter-compaction with LDS-staged coalesced stores ------
__global__ __launch_bounds__(TPB)
void scatter_kernel(const float* __restrict__ x, const ull* __restrict__ mT,
                    const ull* __restrict__ mFp, const ull* __restrict__ mNeg,
                    const int* __restrict__ oPos, const int* __restrict__ oCh,
                    const int* __restrict__ rUseFp,
                    float* __restrict__ xp, float* __restrict__ xf) {
    int tile = blockIdx.x;
    int tid = threadIdx.x;
    int r = tile >> 7;
    bool useFp = rUseFp[r] != 0;
    int widx = tile * WORDS_PER_TILE + (tid >> 3);
    int shift = (tid & 7) * 8;
    unsigned bT = (unsigned)(mT[widx] >> shift) & 0xFF;
    ull chw = useFp ? mFp[widx] : mNeg[widx];
    unsigned bCh = (unsigned)(chw >> shift) & 0xFF;
    const float4* x4 = (const float4*)x;
    int b4 = tile * (TILE / 4) + tid * 2;
    float4 a = x4[b4], b = x4[b4 + 1];
    float xv[8] = {a.x, a.y, a.z, a.w, b.x, b.y, b.z, b.w};
    int p = __popc(bT), c = __popc(bCh);
    __shared__ int s[TPB];
    __shared__ float bufP[TILE], bufC[TILE];
    int v = p | (c << 16);
    s[tid] = v;
    __syncthreads();
    for (int off = 1; off < TPB; off <<= 1) {
        int add = tid >= off ? s[tid - off] : 0;
        __syncthreads();
        s[tid] += add;
        __syncthreads();
    }
    int excl = s[tid] - v;
    int ep = excl & 0xFFFF;
    int ec = excl >> 16;
#pragma unroll
    for (int e = 0; e < 8; ++e) {
        if ((bT >> e) & 1) bufP[ep++] = xv[e];
        if ((bCh >> e) & 1) bufC[ec++] = xv[e];
    }
    __syncthreads();
    int tot = s[TPB - 1];
    int P = tot & 0xFFFF, C = tot >> 16;
    int rL = r << LOG2L;
    int pbase = rL + oPos[tile];
    for (int i = tid; i < P; i += TPB) xp[pbase + i] = bufP[i];
    int cbase = rL + oCh[tile];
    for (int i = tid; i < C; i += TPB) xf[cbase + i] = bufC[i];
}

// ------ K4: loss. Fast path: dup-centric, straight-line, all loads independent. ------
__global__ __launch_bounds__(TPB)
void loss_kernel(const float* __restrict__ x, const ull* __restrict__ mT,
                 const float* __restrict__ xp, const float* __restrict__ xf,
                 const int* __restrict__ rCp, const int* __restrict__ rCc,
                 const ull* __restrict__ rMp, const ull* __restrict__ rMc,
                 double* __restrict__ rowAcc) {
    int b = blockIdx.x;
    int r = b >> 6;                 // LBLK=64 blocks per row
    int blk = b & 63;
    int rL = r << LOG2L;
    int cp = rCp[r], cc = rCc[r];   // wave-uniform scalars
    const float* xr = x + rL;
    const float* xpr = xp + rL;
    const ull* mtr = mT + (rL >> 6);
    int tid = threadIdx.x;
    float local = 0.0f;

    if (cc == 0 && cp * 3 >= L && cp > 0) {
        // dup_fp == -5 everywhere. Each xp[j] serves l = j, j+cp, j+2cp (when < L).
        for (int base = blk * JBLK; base < cp; base += LBLK * JBLK) {
            int j0 = base + tid * JT;   // this thread's 8 consecutive j
            if (j0 + JT <= cp) {
                // ---- straight-line: 4x float4 + 8 guarded scalars + 3 mask words ----
                float4 a0 = *(const float4*)(xpr + j0);
                float4 a1 = *(const float4*)(xpr + j0 + 4);
                float4 b0 = *(const float4*)(xr + j0);
                float4 b1 = *(const float4*)(xr + j0 + 4);
                int l2_0 = j0 + cp;
                float c2[8];
                bool v2[8];
#pragma unroll
                for (int k = 0; k < 8; ++k) {
                    int l2 = l2_0 + k;
                    v2[k] = l2 < L;
                    c2[k] = v2[k] ? xr[l2] : 0.0f;
                }
                ull wj = mtr[j0 >> 6];
                int w2i = l2_0 >> 6;
                ull w2a = mtr[w2i];
                ull w2b = mtr[(w2i + 1 < WORDS_PER_ROW) ? w2i + 1 : WORDS_PER_ROW - 1];
                float dps[8] = {a0.x, a0.y, a0.z, a0.w, a1.x, a1.y, a1.z, a1.w};
                float xjs[8] = {b0.x, b0.y, b0.z, b0.w, b1.x, b1.y, b1.z, b1.w};
                unsigned pj = (unsigned)(j0 & 63);
                unsigned p2 = (unsigned)(l2_0 & 63);
#pragma unroll
                for (int k = 0; k < 8; ++k) {
                    float dp = dps[k];
                    float sim1 = dp * xjs[k];
                    unsigned t1 = (unsigned)(wj >> (pj + k)) & 1u;
                    float e = softplus_f(sim1) - (t1 ? sim1 : 0.0f);
                    float n = 1.0f;
                    if (v2[k]) {
                        unsigned pp = p2 + k;
                        ull w = (pp < 64) ? w2a : w2b;
                        unsigned t2 = (unsigned)(w >> (pp & 63)) & 1u;
                        float sim2 = dp * c2[k];
                        e += softplus_f(sim2) - (t2 ? sim2 : 0.0f);
                        n += 1.0f;
                    }
                    int l3 = l2_0 + k + cp;
                    if (l3 < L) {
                        float x3 = xr[l3];
                        unsigned t3 = (unsigned)(mtr[l3 >> 6] >> (l3 & 63)) & 1u;
                        float sim3 = dp * x3;
                        e += softplus_f(sim3) - (t3 ? sim3 : 0.0f);
                        n += 1.0f;
                    }
                    e += n * (softplus_f(-dp) + 0.1f * softplus_f(-5.0f * dp));
                    local += e;
                }
            } else {
                // tail: per-element guarded
#pragma unroll
                for (int k = 0; k < JT; ++k) {
                    int j = j0 + k;
                    if (j < cp) {
                        float dp = xpr[j];
                        float x1 = xr[j];
                        unsigned t1 = (unsigned)(mtr[j >> 6] >> (j & 63)) & 1u;
                        float sim1 = dp * x1;
                        float e = softplus_f(sim1) - (t1 ? sim1 : 0.0f);
                        float n = 1.0f;
                        int l2 = j + cp;
                        if (l2 < L) {
                            float x2 = xr[l2];
                            unsigned t2 = (unsigned)(mtr[l2 >> 6] >> (l2 & 63)) & 1u;
                            float sim2 = dp * x2;
                            e += softplus_f(sim2) - (t2 ? sim2 : 0.0f);
                            n += 1.0f;
                        }
                        int l3 = j + 2 * cp;
                        if (l3 < L) {
                            float x3 = xr[l3];
                            unsigned t3 = (unsigned)(mtr[l3 >> 6] >> (l3 & 63)) & 1u;
                            float sim3 = dp * x3;
                            e += softplus_f(sim3) - (t3 ? sim3 : 0.0f);
                            n += 1.0f;
                        }
                        e += n * (softplus_f(-dp) + 0.1f * softplus_f(-5.0f * dp));
                        local += e;
                    }
                }
            }
        }
    } else {
        // generic element-centric path (magic-mod gathers); correctness fallback
        int cb = blk * CHUNK;
        ull Mp = rMp[r], Mc = rMc[r];
        const float* xfr = xf + rL;
        const float4* x4 = (const float4*)(xr + cb);
#pragma unroll
        for (int g = 0; g < G; ++g) {
            int o4 = g * TPB + tid;
            unsigned l = (unsigned)(cb + (o4 << 2));
            float4 xv = x4[o4];
            unsigned tb = (unsigned)(mtr[l >> 6] >> (l & 63)) & 0xFu;
            float dps[4], dfs[4];
            if (cp > 0) {
                unsigned d = (unsigned)cp;
                unsigned q = (unsigned)(((ull)l * Mp) >> 40);
                unsigned m0 = l - q * d;
                unsigned m1 = m0 + 1; if (m1 == d) m1 = 0;
                unsigned m2 = m1 + 1; if (m2 == d) m2 = 0;
                unsigned m3 = m2 + 1; if (m3 == d) m3 = 0;
                dps[0] = xpr[m0]; dps[1] = xpr[m1]; dps[2] = xpr[m2]; dps[3] = xpr[m3];
            } else {
                dps[0] = dps[1] = dps[2] = dps[3] = 5.0f;
            }
            if (cc > 0) {
                unsigned d = (unsigned)cc;
                unsigned q = (unsigned)(((ull)l * Mc) >> 40);
                unsigned m0 = l - q * d;
                unsigned m1 = m0 + 1; if (m1 == d) m1 = 0;
                unsigned m2 = m1 + 1; if (m2 == d) m2 = 0;
                unsigned m3 = m2 + 1; if (m3 == d) m3 = 0;
                dfs[0] = xfr[m0]; dfs[1] = xfr[m1]; dfs[2] = xfr[m2]; dfs[3] = xfr[m3];
            } else {
                dfs[0] = dfs[1] = dfs[2] = dfs[3] = -5.0f;
            }
            float xs[4] = {xv.x, xv.y, xv.z, xv.w};
#pragma unroll
            for (int k = 0; k < 4; ++k) {
                float dp = dps[k];
                float sim = dp * xs[k];
                float e = softplus_f(sim) + softplus_f(-dp) + 0.1f * softplus_f(dp * dfs[k]);
                if ((tb >> k) & 1) e -= sim;
                local += e;
            }
        }
    }

    // ---- wave shuffle reduce, tiny LDS combine, one double atomic per block to row slot ----
#pragma unroll
    for (int m = 1; m < 64; m <<= 1) local += __shfl_xor(local, m, 64);
    __shared__ double sw[4];
    int lane = tid & 63, wv = tid >> 6;
    if (lane == 0) sw[wv] = (double)local;
    __syncthreads();
    if (tid == 0) {
        double s = sw[0] + sw[1] + sw[2] + sw[3];
        atomicAdd(&rowAcc[r], s);
    }
}

// ------ K5: finalize (tiny) ------
__global__ void finalize_kernel(const double* __restrict__ rowAcc, float* __restrict__ out,
                                double inv_ntot, int R) {
    if (threadIdx.x == 0) {
        double s = 0.0;
        for (int r = 0; r < R; ++r) s += rowAcc[r];
        out[0] = (float)(s * inv_ntot);
    }
}

extern "C" void kernel_launch(void* const* d_in, const int* in_sizes, int n_in,
                              void* d_out, int out_size, void* d_ws, size_t ws_size,
                              hipStream_t stream) {
    const float* x = (const float*)d_in[0];
    const float* t = (const float*)d_in[1];
    float* out = (float*)d_out;

    int ntot = in_sizes[0];          // 12,582,912
    int R = ntot >> LOG2L;           // 48
    int numTiles = ntot / TILE;      // 6144
    int nwords = ntot / 64;          // 196,608
    int nMaskBlk = ntot / (SPB * W); // 768

    char* ws = (char*)d_ws;
    size_t off = 0;
    auto alloc = [&](size_t bytes) {
        size_t p = off;
        off = (off + bytes + 255) & ~(size_t)255;
        return (void*)(ws + p);
    };
    double* rowAcc = (double*)alloc(R * sizeof(double));
    ull* mT   = (ull*)alloc((size_t)nwords * 8);
    ull* mFp  = (ull*)alloc((size_t)nwords * 8);
    ull* mNeg = (ull*)alloc((size_t)nwords * 8);
    int* cPos = (int*)alloc(numTiles * sizeof(int));
    int* cFp  = (int*)alloc(numTiles * sizeof(int));
    int* cNeg = (int*)alloc(numTiles * sizeof(int));
    int* oPos = (int*)alloc(numTiles * sizeof(int));
    int* oCh  = (int*)alloc(numTiles * sizeof(int));
    int* rCp = (int*)alloc(R * sizeof(int));
    int* rCc = (int*)alloc(R * sizeof(int));
    int* rUseFp = (int*)alloc(R * sizeof(int));
    ull* rMp = (ull*)alloc(R * sizeof(ull));
    ull* rMc = (ull*)alloc(R * sizeof(ull));
    float* xp = (float*)alloc((size_t)ntot * sizeof(float));
    float* xf = (float*)alloc((size_t)ntot * sizeof(float));

    fused_mask_kernel<<<nMaskBlk, TPB, 0, stream>>>(x, t, mT, mFp, mNeg, cPos, cFp, cNeg,
                                                    rowAcc);
    scan_kernel<<<R, TILES_PER_ROW, 0, stream>>>(cPos, cFp, cNeg, oPos, oCh,
                                                 rCp, rCc, rMp, rMc, rUseFp);
    scatter_kernel<<<numTiles, TPB, 0, stream>>>(x, mT, mFp, mNeg, oPos, oCh, rUseFp, xp, xf);
    loss_kernel<<<R * LBLK, TPB, 0, stream>>>(x, mT, xp, xf, rCp, rCc, rMp, rMc, rowAcc);
    finalize_kernel<<<1, 64, 0, stream>>>(rowAcc, out, 1.0 / (double)ntot, R);
}